// Round 1
// baseline (500.336 us; speedup 1.0000x reference)
//
#include <hip/hip_runtime.h>
#include <math.h>

#define B    256
#define I    1152
#define O    10
#define DIN  8
#define DOUT 16
#define OE   160          // O*DOUT
#define XROW 9216         // I*DIN
#define WROW 1280         // O*DIN*DOUT

// ---------------------------------------------------------------------------
// SPART: partial s[b,o,e] over i-chunks.
//   s[b,oe] += sum_{i in chunk} c[i,o] * sum_d x[b,i,d] * W[i,o,d,e]
// grid = 4*P blocks (P i-chunks x 4 b-tiles of 64), 256 threads.
// thread t: b = bt*64 + (t>>2), e-quad = (t&3)*4 -> 10 float4 accumulators.
// W loads: 16 lanes broadcast same float4 group -> one 64B L2 line / wave instr.
// ---------------------------------------------------------------------------
__global__ __launch_bounds__(256) void spart_kernel(
    const float* __restrict__ x, const float* __restrict__ W,
    const float* __restrict__ c, float* __restrict__ sp,
    int P, int chunk, int first)
{
    int blk = blockIdx.x;
    int ic  = blk % P;
    int bt  = blk / P;
    int t   = threadIdx.x;
    int b   = bt * 64 + (t >> 2);
    int e0  = (t & 3) * 4;
    int i0  = ic * chunk;

    float4 acc[O];
#pragma unroll
    for (int o = 0; o < O; ++o) acc[o] = make_float4(0.f, 0.f, 0.f, 0.f);

    for (int il = 0; il < chunk; ++il) {
        int i = i0 + il;
        const float4* xp = (const float4*)(x + (b * I + i) * DIN);
        float4 xa = xp[0];
        float4 xb = xp[1];
        float xs[8] = {xa.x, xa.y, xa.z, xa.w, xb.x, xb.y, xb.z, xb.w};
        const float* wb = W + i * WROW + e0;
#pragma unroll
        for (int o = 0; o < O; ++o) {
            const float4* wp = (const float4*)(wb + o * (DIN * DOUT));
            float4 s4 = make_float4(0.f, 0.f, 0.f, 0.f);
#pragma unroll
            for (int d = 0; d < 8; ++d) {
                float4 w = wp[d * 4];           // W[i,o,d,e0..e0+3]
                s4.x = fmaf(xs[d], w.x, s4.x);
                s4.y = fmaf(xs[d], w.y, s4.y);
                s4.z = fmaf(xs[d], w.z, s4.z);
                s4.w = fmaf(xs[d], w.w, s4.w);
            }
            float cv = first ? 0.1f : c[i * O + o];
            acc[o].x = fmaf(cv, s4.x, acc[o].x);
            acc[o].y = fmaf(cv, s4.y, acc[o].y);
            acc[o].z = fmaf(cv, s4.z, acc[o].z);
            acc[o].w = fmaf(cv, s4.w, acc[o].w);
        }
    }

    float* dst = sp + (size_t)ic * (B * OE) + b * OE + e0;
#pragma unroll
    for (int o = 0; o < O; ++o) *(float4*)(dst + o * DOUT) = acc[o];
}

// ---------------------------------------------------------------------------
// VRED: sum P partials + squash over e (16 lanes), write v (or final output).
// grid = 160 blocks x 256 threads = 40960 elements, lane low 4 bits == e.
// ---------------------------------------------------------------------------
__global__ __launch_bounds__(256) void vred_kernel(
    const float* __restrict__ sp, float* __restrict__ dst, int P)
{
    int g = blockIdx.x * 256 + threadIdx.x;     // [b][o][e] flat
    float s = 0.f;
    for (int ic = 0; ic < P; ++ic) s += sp[(size_t)ic * (B * OE) + g];

    float ss = s * s;
    ss += __shfl_xor(ss, 1, 16);
    ss += __shfl_xor(ss, 2, 16);
    ss += __shfl_xor(ss, 4, 16);
    ss += __shfl_xor(ss, 8, 16);
    // squash: ss/(1+ss) * s/sqrt(ss) == s * sqrt(ss)/(1+ss)
    float f = sqrtf(ss) / (1.f + ss);
    dst[g] = s * f;
}

// ---------------------------------------------------------------------------
// AGREE (+ fused b-update and softmax -> c for the next iteration).
// One block per i (1152 blocks, 320 threads = 2 d-groups x 160 oe columns).
//   G[d,oe] = sum_b x[b,i,d] * v[b,oe]          (rank-256 outer products)
//   agree[o] = (1/B) sum_{d,e} W[i,o,d,e]*G[d,oe]
//   b[i,o] += agree[o];  c[i,:] = softmax(b[i,:])
// ---------------------------------------------------------------------------
__global__ __launch_bounds__(320) void agree_kernel(
    const float* __restrict__ x, const float* __restrict__ W,
    const float* __restrict__ v, float* __restrict__ blog,
    float* __restrict__ c, int first)
{
    int i  = blockIdx.x;
    int t  = threadIdx.x;
    int dg = (t >= OE) ? 1 : 0;
    int oe = t - dg * OE;
    int d0 = dg * 4;

    float a0 = 0.f, a1 = 0.f, a2 = 0.f, a3 = 0.f;
    const float* xp = x + i * DIN + d0;
    const float* vp = v + oe;
#pragma unroll 4
    for (int bb = 0; bb < B; ++bb) {
        float vv = vp[bb * OE];
        float4 xq = *(const float4*)(xp + (size_t)bb * XROW);
        a0 = fmaf(xq.x, vv, a0);
        a1 = fmaf(xq.y, vv, a1);
        a2 = fmaf(xq.z, vv, a2);
        a3 = fmaf(xq.w, vv, a3);
    }

    __shared__ float G[DIN * OE];
    __shared__ float brow[O];
    G[(d0 + 0) * OE + oe] = a0;
    G[(d0 + 1) * OE + oe] = a1;
    G[(d0 + 2) * OE + oe] = a2;
    G[(d0 + 3) * OE + oe] = a3;
    __syncthreads();

    if (t < OE) {
        int o = t >> 4;
        const float* wr = W + i * WROW + o * (DIN * DOUT) + (t & 15);
        float p = 0.f;
#pragma unroll
        for (int d = 0; d < DIN; ++d) p = fmaf(wr[d * DOUT], G[d * OE + t], p);
        // reduce over e within each aligned 16-lane group
        p += __shfl_xor(p, 8, 16);
        p += __shfl_xor(p, 4, 16);
        p += __shfl_xor(p, 2, 16);
        p += __shfl_xor(p, 1, 16);
        if ((t & 15) == 0) {
            float bo = first ? 0.f : blog[i * O + o];
            bo += p * (1.f / (float)B);
            blog[i * O + o] = bo;
            brow[o] = bo;
        }
    }
    __syncthreads();

    if (t == 0) {
        float m = brow[0];
#pragma unroll
        for (int o = 1; o < O; ++o) m = fmaxf(m, brow[o]);
        float ex[O];
        float sum = 0.f;
#pragma unroll
        for (int o = 0; o < O; ++o) { ex[o] = __expf(brow[o] - m); sum += ex[o]; }
        float inv = 1.f / sum;
#pragma unroll
        for (int o = 0; o < O; ++o) c[i * O + o] = ex[o] * inv;
    }
}

// ---------------------------------------------------------------------------
extern "C" void kernel_launch(void* const* d_in, const int* in_sizes, int n_in,
                              void* d_out, int out_size, void* d_ws, size_t ws_size,
                              hipStream_t stream)
{
    const float* x = (const float*)d_in[0];   // [256,1152,8]
    const float* W = (const float*)d_in[1];   // [1152,10,8,16]
    float* out = (float*)d_out;               // [256,10,16,1] flat = 40960
    float* ws  = (float*)d_ws;

    float* blog = ws;                         // 11520 floats
    float* c    = ws + 11520;                 // 11520 floats
    float* vbuf = ws + 23040;                 // 40960 floats
    float* sp   = ws + 64000;                 // P * 40960 floats

    size_t wsf   = ws_size / sizeof(float);
    size_t avail = (wsf > 64000) ? (wsf - 64000) : 0;
    static const int cand[] = {72, 48, 36, 24, 18, 16, 12, 9, 8, 6, 4, 3, 2, 1};
    int P = 1;
    for (int k = 0; k < (int)(sizeof(cand) / sizeof(int)); ++k) {
        if ((size_t)cand[k] * (B * OE) <= avail) { P = cand[k]; break; }
    }
    int chunk = I / P;
    dim3 gs(4 * P), bs(256);

    // ---- iteration 1 (b = 0 -> c uniform 0.1, folded via `first`) ----
    spart_kernel<<<gs, bs, 0, stream>>>(x, W, c, sp, P, chunk, 1);
    vred_kernel<<<160, 256, 0, stream>>>(sp, vbuf, P);
    agree_kernel<<<I, 320, 0, stream>>>(x, W, vbuf, blog, c, 1);
    // ---- iteration 2 ----
    spart_kernel<<<gs, bs, 0, stream>>>(x, W, c, sp, P, chunk, 0);
    vred_kernel<<<160, 256, 0, stream>>>(sp, vbuf, P);
    agree_kernel<<<I, 320, 0, stream>>>(x, W, vbuf, blog, c, 0);
    // ---- iteration 3 (no agree needed; squash straight into d_out) ----
    spart_kernel<<<gs, bs, 0, stream>>>(x, W, c, sp, P, chunk, 0);
    vred_kernel<<<160, 256, 0, stream>>>(sp, out, P);
}

// Round 2
// 247.087 us; speedup vs baseline: 2.0249x; 2.0249x over previous
//
#include <hip/hip_runtime.h>
#include <math.h>

#define B    256
#define I    1152
#define O    10
#define DIN  8
#define DOUT 16
#define OE   160          // O*DOUT
#define XROW 9216         // I*DIN
#define WROW 1280         // O*DIN*DOUT
#define BT   128          // b-rows per spart block

// ---------------------------------------------------------------------------
// SPART v2: LDS-staged split-K GEMM.
//   s[b,oe] += sum_{i in chunk} sum_d x[b,i,d] * (c[i,o]*W[i,o,d,e])
// grid = 2*P blocks (P i-chunks x 2 b-tiles of 128), 256 threads.
// Stage NI=2 i-rows of W (c-scaled) + x-tile in LDS; thread owns 2 b-rows x
// 10 o x 4 e = 80 accumulators so each ds_read_b128 of W feeds 8 FMAs.
// ---------------------------------------------------------------------------
__global__ __launch_bounds__(256) void spart_kernel(
    const float* __restrict__ x, const float* __restrict__ W,
    const float* __restrict__ c, float* __restrict__ sp,
    int P, int chunk, int first)
{
    __shared__ float  Wt[2][WROW];     // c-scaled W rows for the i-pair (10 KB)
    __shared__ float4 Xt[2][2][BT];    // [i-of-pair][d-half][row]      (8 KB)

    int blk = blockIdx.x;
    int ic  = blk % P;
    int bt  = blk / P;
    int b0  = bt * BT;
    int t   = threadIdx.x;
    int rr  = t >> 2;                  // 0..63  (rows rr and rr+64)
    int q   = t & 3;                   // e-quad
    int i0  = ic * chunk;

    float4 acc[2][O];
#pragma unroll
    for (int r = 0; r < 2; ++r)
#pragma unroll
        for (int o = 0; o < O; ++o) acc[r][o] = make_float4(0.f, 0.f, 0.f, 0.f);

    for (int s0 = 0; s0 < chunk; s0 += 2) {
        int ibase = i0 + s0;

        // ---- coop stage W (scaled by c) : 640 float4 ----
#pragma unroll
        for (int k = 0; k < 3; ++k) {
            int idx = t + 256 * k;
            if (idx < 640) {
                int s   = idx / 320;
                int rem = idx - s * 320;           // float4 index within row
                int o   = rem >> 5;
                float4 w4 = *(const float4*)(W + (ibase + s) * WROW + rem * 4);
                float  cv = first ? 0.1f : c[(ibase + s) * O + o];
                w4.x *= cv; w4.y *= cv; w4.z *= cv; w4.w *= cv;
                *((float4*)Wt[s] + rem) = w4;
            }
        }
        // ---- coop stage X : 512 float4 (64B contiguous per 4 lanes) ----
#pragma unroll
        for (int k = 0; k < 2; ++k) {
            int idx = t + 256 * k;
            int r = idx >> 2;
            int s = (idx >> 1) & 1;
            int h = idx & 1;
            Xt[s][h][r] =
                *(const float4*)(x + ((size_t)(b0 + r) * I + (ibase + s)) * DIN + h * 4);
        }
        __syncthreads();

        // ---- compute the 2 staged i's ----
#pragma unroll
        for (int s = 0; s < 2; ++s) {
            float4 xa0 = Xt[s][0][rr];
            float4 xa1 = Xt[s][1][rr];
            float4 xb0 = Xt[s][0][rr + 64];
            float4 xb1 = Xt[s][1][rr + 64];
            float xsA[8] = {xa0.x, xa0.y, xa0.z, xa0.w, xa1.x, xa1.y, xa1.z, xa1.w};
            float xsB[8] = {xb0.x, xb0.y, xb0.z, xb0.w, xb1.x, xb1.y, xb1.z, xb1.w};
            const float4* wrow = (const float4*)Wt[s];
#pragma unroll
            for (int o = 0; o < O; ++o) {
#pragma unroll
                for (int d = 0; d < 8; ++d) {
                    float4 w = wrow[o * 32 + d * 4 + q];   // broadcast, conflict-free
                    acc[0][o].x = fmaf(xsA[d], w.x, acc[0][o].x);
                    acc[0][o].y = fmaf(xsA[d], w.y, acc[0][o].y);
                    acc[0][o].z = fmaf(xsA[d], w.z, acc[0][o].z);
                    acc[0][o].w = fmaf(xsA[d], w.w, acc[0][o].w);
                    acc[1][o].x = fmaf(xsB[d], w.x, acc[1][o].x);
                    acc[1][o].y = fmaf(xsB[d], w.y, acc[1][o].y);
                    acc[1][o].z = fmaf(xsB[d], w.z, acc[1][o].z);
                    acc[1][o].w = fmaf(xsB[d], w.w, acc[1][o].w);
                }
            }
        }
        __syncthreads();
    }

    float* dst0 = sp + (size_t)ic * (B * OE) + (b0 + rr) * OE + q * 4;
    float* dst1 = dst0 + 64 * OE;
#pragma unroll
    for (int o = 0; o < O; ++o) {
        *(float4*)(dst0 + o * DOUT) = acc[0][o];
        *(float4*)(dst1 + o * DOUT) = acc[1][o];
    }
}

// ---------------------------------------------------------------------------
// VRED: sum P partials + squash over e (16 lanes), write v (or final output).
// ---------------------------------------------------------------------------
__global__ __launch_bounds__(256) void vred_kernel(
    const float* __restrict__ sp, float* __restrict__ dst, int P)
{
    int g = blockIdx.x * 256 + threadIdx.x;     // [b][o][e] flat
    float s = 0.f;
#pragma unroll 4
    for (int ic = 0; ic < P; ++ic) s += sp[(size_t)ic * (B * OE) + g];

    float ss = s * s;
    ss += __shfl_xor(ss, 1, 16);
    ss += __shfl_xor(ss, 2, 16);
    ss += __shfl_xor(ss, 4, 16);
    ss += __shfl_xor(ss, 8, 16);
    float f = sqrtf(ss) / (1.f + ss);           // squash factor
    dst[g] = s * f;
}

// ---------------------------------------------------------------------------
// AGREE (+ fused b-update and softmax -> c). One block per i, 320 threads.
// x[:,i,:] staged in LDS; v-load chain unrolled x4 to pipeline L2 latency.
// ---------------------------------------------------------------------------
__global__ __launch_bounds__(320) void agree_kernel(
    const float* __restrict__ x, const float* __restrict__ W,
    const float* __restrict__ v, float* __restrict__ blog,
    float* __restrict__ c, int first)
{
    int i  = blockIdx.x;
    int t  = threadIdx.x;
    int dg = (t >= OE) ? 1 : 0;
    int oe = t - dg * OE;

    __shared__ float4 Xl[B][2];        // x[b, i, 0:8] as two float4 (8 KB)
    __shared__ float  G[DIN * OE];
    __shared__ float  brow[O];

#pragma unroll
    for (int k = 0; k < 2; ++k) {
        int idx = t + 320 * k;
        if (idx < 512) {
            int r = idx >> 1;
            int h = idx & 1;
            Xl[r][h] = *(const float4*)(x + (size_t)r * XROW + i * DIN + h * 4);
        }
    }
    __syncthreads();

    float a0 = 0.f, a1 = 0.f, a2 = 0.f, a3 = 0.f;
    const float* vp = v + oe;
#pragma unroll 4
    for (int bb = 0; bb < B; ++bb) {
        float  vv = vp[bb * OE];
        float4 xq = Xl[bb][dg];
        a0 = fmaf(xq.x, vv, a0);
        a1 = fmaf(xq.y, vv, a1);
        a2 = fmaf(xq.z, vv, a2);
        a3 = fmaf(xq.w, vv, a3);
    }

    int d0 = dg * 4;
    G[(d0 + 0) * OE + oe] = a0;
    G[(d0 + 1) * OE + oe] = a1;
    G[(d0 + 2) * OE + oe] = a2;
    G[(d0 + 3) * OE + oe] = a3;
    __syncthreads();

    if (t < OE) {
        int o = t >> 4;
        const float* wr = W + (size_t)i * WROW + o * (DIN * DOUT) + (t & 15);
        float p = 0.f;
#pragma unroll
        for (int d = 0; d < DIN; ++d) p = fmaf(wr[d * DOUT], G[d * OE + t], p);
        p += __shfl_xor(p, 8, 16);
        p += __shfl_xor(p, 4, 16);
        p += __shfl_xor(p, 2, 16);
        p += __shfl_xor(p, 1, 16);
        if ((t & 15) == 0) {
            float bo = first ? 0.f : blog[i * O + o];
            bo += p * (1.f / (float)B);
            blog[i * O + o] = bo;
            brow[o] = bo;
        }
    }
    __syncthreads();

    if (t == 0) {
        float m = brow[0];
#pragma unroll
        for (int o = 1; o < O; ++o) m = fmaxf(m, brow[o]);
        float ex[O];
        float sum = 0.f;
#pragma unroll
        for (int o = 0; o < O; ++o) { ex[o] = __expf(brow[o] - m); sum += ex[o]; }
        float inv = 1.f / sum;
#pragma unroll
        for (int o = 0; o < O; ++o) c[i * O + o] = ex[o] * inv;
    }
}

// ---------------------------------------------------------------------------
extern "C" void kernel_launch(void* const* d_in, const int* in_sizes, int n_in,
                              void* d_out, int out_size, void* d_ws, size_t ws_size,
                              hipStream_t stream)
{
    const float* x = (const float*)d_in[0];   // [256,1152,8]
    const float* W = (const float*)d_in[1];   // [1152,10,8,16]
    float* out = (float*)d_out;               // [256,10,16,1] flat = 40960
    float* ws  = (float*)d_ws;

    float* blog = ws;                         // 11520 floats
    float* c    = ws + 11520;                 // 11520 floats
    float* vbuf = ws + 23040;                 // 40960 floats
    float* sp   = ws + 64000;                 // P * 40960 floats

    size_t wsf   = ws_size / sizeof(float);
    size_t avail = (wsf > 64000) ? (wsf - 64000) : 0;
    // P must divide 1152 with even chunk (NI=2 staging)
    static const int cand[] = {288, 144, 96, 72, 48, 36, 24, 18, 16, 12, 8, 6, 4, 2, 1};
    int P = 1;
    for (int k = 0; k < (int)(sizeof(cand) / sizeof(int)); ++k) {
        if ((size_t)cand[k] * (B * OE) <= avail) { P = cand[k]; break; }
    }
    int chunk = I / P;
    dim3 gs(2 * P), bs(256);

    // ---- iteration 1 (b = 0 -> c uniform 0.1, folded via `first`) ----
    spart_kernel<<<gs, bs, 0, stream>>>(x, W, c, sp, P, chunk, 1);
    vred_kernel<<<160, 256, 0, stream>>>(sp, vbuf, P);
    agree_kernel<<<I, 320, 0, stream>>>(x, W, vbuf, blog, c, 1);
    // ---- iteration 2 ----
    spart_kernel<<<gs, bs, 0, stream>>>(x, W, c, sp, P, chunk, 0);
    vred_kernel<<<160, 256, 0, stream>>>(sp, vbuf, P);
    agree_kernel<<<I, 320, 0, stream>>>(x, W, vbuf, blog, c, 0);
    // ---- iteration 3 (no agree needed; squash straight into d_out) ----
    spart_kernel<<<gs, bs, 0, stream>>>(x, W, c, sp, P, chunk, 0);
    vred_kernel<<<160, 256, 0, stream>>>(sp, out, P);
}

// Round 3
// 164.490 us; speedup vs baseline: 3.0417x; 1.5021x over previous
//
#include <hip/hip_runtime.h>
#include <math.h>

#define B    256
#define I    1152
#define O    10
#define DIN  8
#define DOUT 16
#define OE   160          // O*DOUT
#define XROW 9216         // I*DIN (also K of the s-GEMM)
#define WROW 1280         // O*DIN*DOUT
#define PSPLIT 72         // split-K partials
#define CHUNK  16         // i per spart block
#define SI     8          // i per staging round (K-window 64)

typedef __attribute__((ext_vector_type(8))) short short8;
typedef __attribute__((ext_vector_type(4))) float floatx4;

__device__ __forceinline__ unsigned short f2bf(float f) {
    unsigned u = __builtin_bit_cast(unsigned, f);
    u += 0x7fffu + ((u >> 16) & 1u);          // RNE
    return (unsigned short)(u >> 16);
}
__device__ __forceinline__ float bf2f(unsigned short h) {
    unsigned u = ((unsigned)h) << 16;
    return __builtin_bit_cast(float, u);
}

// ---------------------------------------------------------------------------
// XSPLIT: x (fp32) -> xh + xl (bf16 pair), layout [b][k] k-contiguous.
// ---------------------------------------------------------------------------
__global__ __launch_bounds__(256) void xsplit_kernel(
    const float* __restrict__ x,
    unsigned short* __restrict__ xh, unsigned short* __restrict__ xl)
{
    int g = blockIdx.x * 256 + threadIdx.x;       // float4 index
    float4 v = ((const float4*)x)[g];
    ushort4 h, l;
    h.x = f2bf(v.x); l.x = f2bf(v.x - bf2f(h.x));
    h.y = f2bf(v.y); l.y = f2bf(v.y - bf2f(h.y));
    h.z = f2bf(v.z); l.z = f2bf(v.z - bf2f(h.z));
    h.w = f2bf(v.w); l.w = f2bf(v.w - bf2f(h.w));
    ((ushort4*)xh)[g] = h;
    ((ushort4*)xl)[g] = l;
}

// ---------------------------------------------------------------------------
// SPART v3: MFMA bf16 hi/lo split-K GEMM.
//   s[b,oe] = sum_k (xh+xl)[b,k] * (wh+wl)[k,oe],  wc = c[i,o]*W scaled in staging
//   3 MFMAs per tile-step: xh*wh + xh*wl + xl*wh  (xl*wl dropped, ~2^-18)
// grid = 4*PSPLIT blocks: bid -> ic=bid>>2, mb=(bid>>1)&1 (128 b-rows),
// nb=bid&1 (80 oe cols). Block = 4 waves; wave tile M=32 x N=80
// (2 m-tiles x 5 n-tiles of 16x16, acc 40 VGPR).
// LDS XOR-swizzle: 16B chunk c at row r stored at chunk c^(r&7) -> all b128
// frag reads/writes hit the 8-access/bank minimum (conflict-free).
// ---------------------------------------------------------------------------
__global__ __launch_bounds__(256) void spart_mfma(
    const unsigned short* __restrict__ xh, const unsigned short* __restrict__ xl,
    const float* __restrict__ W, const float* __restrict__ c,
    float* __restrict__ sp, int first)
{
    __shared__ unsigned short Wh[80 * 64], Wl[80 * 64];    // [oe-local][k-window]
    __shared__ unsigned short Xh[128 * 64], Xl[128 * 64];  // [b-local ][k-window]

    int bid = blockIdx.x;
    int ic  = bid >> 2;
    int mb  = (bid >> 1) & 1;
    int nb  = bid & 1;
    int b0  = mb * 128;
    int oe0 = nb * 80;
    int o0  = nb * 5;
    int i0  = ic * CHUNK;

    int t    = threadIdx.x;
    int w    = t >> 6;
    int lane = t & 63;
    int l15  = lane & 15;
    int q    = lane >> 4;

    floatx4 acc[2][5];
#pragma unroll
    for (int mt = 0; mt < 2; ++mt)
#pragma unroll
        for (int nt = 0; nt < 5; ++nt) acc[mt][nt] = (floatx4)(0.f);

#pragma unroll
    for (int round = 0; round < CHUNK / SI; ++round) {
        int si0 = i0 + round * SI;
        if (round) __syncthreads();

        // ---- stage W: scale by c, split hi/lo, write [oe][k] swizzled ----
#pragma unroll
        for (int r = 0; r < 3; ++r) {
            int p = t + 256 * r;                       // (oe-local, i-local) pair
            if (p < 640) {
                int oeL = p % 80;
                int iL  = p / 80;                      // 0..7
                int o   = o0 + (oeL >> 4);
                int e   = oeL & 15;
                const float* wp = W + (size_t)(si0 + iL) * WROW + o * (DIN * DOUT) + e;
                float cv = first ? 0.1f : c[(si0 + iL) * O + o];
                short8 hv, lv;
#pragma unroll
                for (int d = 0; d < 8; ++d) {
                    float wv = wp[d * DOUT] * cv;
                    unsigned short h = f2bf(wv);
                    hv[d] = (short)h;
                    lv[d] = (short)f2bf(wv - bf2f(h));
                }
                int off = oeL * 64 + ((iL ^ (oeL & 7)) << 3);
                *(short8*)(Wh + off) = hv;
                *(short8*)(Wl + off) = lv;
            }
        }
        // ---- stage X: copy 16B chunks of xh/xl, swizzled ----
#pragma unroll
        for (int r = 0; r < 4; ++r) {
            int cg  = t + 256 * r;                     // 0..1023 chunk id
            int row = cg >> 3;
            int ch  = cg & 7;
            size_t goff = (size_t)(b0 + row) * XROW + (size_t)si0 * 8 + (ch << 3);
            short8 vh = *(const short8*)(xh + goff);
            short8 vl = *(const short8*)(xl + goff);
            int off = row * 64 + ((ch ^ (row & 7)) << 3);
            *(short8*)(Xh + off) = vh;
            *(short8*)(Xl + off) = vl;
        }
        __syncthreads();

        // ---- 2 K-steps of 32 over the staged window ----
#pragma unroll
        for (int ks = 0; ks < 2; ++ks) {
            short8 ah[2], al[2];
#pragma unroll
            for (int mt = 0; mt < 2; ++mt) {
                int rm  = w * 32 + mt * 16 + l15;
                int off = rm * 64 + ((((ks << 2) + q) ^ (rm & 7)) << 3);
                ah[mt] = *(const short8*)(Xh + off);
                al[mt] = *(const short8*)(Xl + off);
            }
#pragma unroll
            for (int nt = 0; nt < 5; ++nt) {
                int rn  = nt * 16 + l15;
                int off = rn * 64 + ((((ks << 2) + q) ^ (rn & 7)) << 3);
                short8 bh = *(const short8*)(Wh + off);
                short8 bl = *(const short8*)(Wl + off);
#pragma unroll
                for (int mt = 0; mt < 2; ++mt) {
                    acc[mt][nt] = __builtin_amdgcn_mfma_f32_16x16x32_bf16(ah[mt], bh, acc[mt][nt], 0, 0, 0);
                    acc[mt][nt] = __builtin_amdgcn_mfma_f32_16x16x32_bf16(ah[mt], bl, acc[mt][nt], 0, 0, 0);
                    acc[mt][nt] = __builtin_amdgcn_mfma_f32_16x16x32_bf16(al[mt], bh, acc[mt][nt], 0, 0, 0);
                }
            }
        }
    }

    // ---- epilogue: C/D layout col=lane&15, row=(lane>>4)*4+reg (m89/m91) ----
    float* base = sp + (size_t)ic * (B * OE);
#pragma unroll
    for (int mt = 0; mt < 2; ++mt) {
        int row0 = b0 + w * 32 + mt * 16 + q * 4;
#pragma unroll
        for (int nt = 0; nt < 5; ++nt) {
            int col = oe0 + nt * 16 + l15;
#pragma unroll
            for (int reg = 0; reg < 4; ++reg)
                base[(row0 + reg) * OE + col] = acc[mt][nt][reg];
        }
    }
}

// ---------------------------------------------------------------------------
// VRED: sum P partials + squash over e (16 lanes), write v (or final output).
// ---------------------------------------------------------------------------
__global__ __launch_bounds__(256) void vred_kernel(
    const float* __restrict__ sp, float* __restrict__ dst)
{
    int g = blockIdx.x * 256 + threadIdx.x;     // [b][o][e] flat
    float s = 0.f;
#pragma unroll 4
    for (int ic = 0; ic < PSPLIT; ++ic) s += sp[(size_t)ic * (B * OE) + g];

    float ss = s * s;
    ss += __shfl_xor(ss, 1, 16);
    ss += __shfl_xor(ss, 2, 16);
    ss += __shfl_xor(ss, 4, 16);
    ss += __shfl_xor(ss, 8, 16);
    float f = sqrtf(ss) / (1.f + ss);           // squash factor
    dst[g] = s * f;
}

// ---------------------------------------------------------------------------
// AGREE (+ fused b-update and softmax -> c). One block per i, 320 threads.
// ---------------------------------------------------------------------------
__global__ __launch_bounds__(320) void agree_kernel(
    const float* __restrict__ x, const float* __restrict__ W,
    const float* __restrict__ v, float* __restrict__ blog,
    float* __restrict__ c, int first)
{
    int i  = blockIdx.x;
    int t  = threadIdx.x;
    int dg = (t >= OE) ? 1 : 0;
    int oe = t - dg * OE;

    __shared__ float4 Xl[B][2];        // x[b, i, 0:8] as two float4 (8 KB)
    __shared__ float  G[DIN * OE];
    __shared__ float  brow[O];

#pragma unroll
    for (int k = 0; k < 2; ++k) {
        int idx = t + 320 * k;
        if (idx < 512) {
            int r = idx >> 1;
            int h = idx & 1;
            Xl[r][h] = *(const float4*)(x + (size_t)r * XROW + i * DIN + h * 4);
        }
    }
    __syncthreads();

    float a0 = 0.f, a1 = 0.f, a2 = 0.f, a3 = 0.f;
    const float* vp = v + oe;
#pragma unroll 8
    for (int bb = 0; bb < B; ++bb) {
        float  vv = vp[bb * OE];
        float4 xq = Xl[bb][dg];
        a0 = fmaf(xq.x, vv, a0);
        a1 = fmaf(xq.y, vv, a1);
        a2 = fmaf(xq.z, vv, a2);
        a3 = fmaf(xq.w, vv, a3);
    }

    int d0 = dg * 4;
    G[(d0 + 0) * OE + oe] = a0;
    G[(d0 + 1) * OE + oe] = a1;
    G[(d0 + 2) * OE + oe] = a2;
    G[(d0 + 3) * OE + oe] = a3;
    __syncthreads();

    if (t < OE) {
        int o = t >> 4;
        const float* wr = W + (size_t)i * WROW + o * (DIN * DOUT) + (t & 15);
        float p = 0.f;
#pragma unroll
        for (int d = 0; d < DIN; ++d) p = fmaf(wr[d * DOUT], G[d * OE + t], p);
        p += __shfl_xor(p, 8, 16);
        p += __shfl_xor(p, 4, 16);
        p += __shfl_xor(p, 2, 16);
        p += __shfl_xor(p, 1, 16);
        if ((t & 15) == 0) {
            float bo = first ? 0.f : blog[i * O + o];
            bo += p * (1.f / (float)B);
            blog[i * O + o] = bo;
            brow[o] = bo;
        }
    }
    __syncthreads();

    if (t == 0) {
        float m = brow[0];
#pragma unroll
        for (int o = 1; o < O; ++o) m = fmaxf(m, brow[o]);
        float ex[O];
        float sum = 0.f;
#pragma unroll
        for (int o = 0; o < O; ++o) { ex[o] = __expf(brow[o] - m); sum += ex[o]; }
        float inv = 1.f / sum;
#pragma unroll
        for (int o = 0; o < O; ++o) c[i * O + o] = ex[o] * inv;
    }
}

// ---------------------------------------------------------------------------
extern "C" void kernel_launch(void* const* d_in, const int* in_sizes, int n_in,
                              void* d_out, int out_size, void* d_ws, size_t ws_size,
                              hipStream_t stream)
{
    const float* x = (const float*)d_in[0];   // [256,1152,8]
    const float* W = (const float*)d_in[1];   // [1152,10,8,16]
    float* out = (float*)d_out;               // [256,10,16,1] flat = 40960

    // workspace layout (bytes): xh 4.72MB | xl 4.72MB | blog | c | v | sp 11.8MB
    unsigned short* xh = (unsigned short*)d_ws;
    unsigned short* xl = xh + (size_t)B * XROW;
    float* blog = (float*)(xl + (size_t)B * XROW);
    float* cbuf = blog + I * O;
    float* vbuf = cbuf + I * O;
    float* sp   = vbuf + B * OE;

    // ---- split x into bf16 hi/lo once (iteration-invariant) ----
    xsplit_kernel<<<(B * XROW) / (256 * 4), 256, 0, stream>>>(x, xh, xl);

    dim3 gs(4 * PSPLIT), bs(256);
    // ---- iteration 1 (b=0 -> c uniform 0.1, folded via `first`) ----
    spart_mfma<<<gs, bs, 0, stream>>>(xh, xl, W, cbuf, sp, 1);
    vred_kernel<<<160, 256, 0, stream>>>(sp, vbuf);
    agree_kernel<<<I, 320, 0, stream>>>(x, W, vbuf, blog, cbuf, 1);
    // ---- iteration 2 ----
    spart_mfma<<<gs, bs, 0, stream>>>(xh, xl, W, cbuf, sp, 0);
    vred_kernel<<<160, 256, 0, stream>>>(sp, vbuf);
    agree_kernel<<<I, 320, 0, stream>>>(x, W, vbuf, blog, cbuf, 0);
    // ---- iteration 3 (squash straight into d_out) ----
    spart_mfma<<<gs, bs, 0, stream>>>(xh, xl, W, cbuf, sp, 0);
    vred_kernel<<<160, 256, 0, stream>>>(sp, out);
}